// Round 1
// baseline (236.395 us; speedup 1.0000x reference)
//
#include <hip/hip_runtime.h>
#include <hip/hip_bf16.h>

// Problem constants (from reference)
#define BATCH   64
#define NMEL    80
#define TFRAME  1000
#define NDEC    1000
#define TENC    200
#define NSPK    100
#define NAUG    10

// Element counts
#define N_MEL   (BATCH * NMEL * TFRAME)     // 5,120,000
#define N_GATE  (BATCH * TFRAME)            // 64,000
#define N_ALIGN (BATCH * NDEC * TENC)       // 12,800,000

// 4-element (16 B fp32) vector units
#define U_MEL   (N_MEL / 4)                 // 1,280,000
#define U_GATE  (N_GATE / 4)                // 16,000
#define U_ALIGN (N_ALIGN / 4)               // 3,200,000

#define BLOCK 256

// R11 = R10 fused into a SINGLE kernel via the last-block-done pattern.
// The separate finalize launch (1-block kernel, ~2us dispatch + ~2-3us run +
// graph-node serialization gap) is replaced by: each block publishes its
// partial with an agent-scope store, increments a zero-initialized module
// counter (acq-rel, agent scope), and the 1830th block finalizes in-place,
// then resets the counter for the next graph replay. No spin-waits -> safe
// at any occupancy; no host API calls -> graph-capture safe; agent-scope
// ops -> correct across non-coherent per-XCD L2s.
#define MEL_NB     1000                      // 1280 units/block (5 float4/lane x 3 streams)
#define ALIGN_NB   782                       // 781 x 4096 units + 1 x 1024 tail
#define ALIGN_FULL 781
#define GATE_NB    16                        // 1024 units/block, bounds-checked
#define SPK_NB     16                        // 4 waves/block x 16 = 64 rows
#define AUG_NB     16                        // 4 waves/block x 16 = 64 rows
#define MEL_B0     0
#define ALIGN_B0   (MEL_B0 + MEL_NB)         // 1000
#define GATE_B0    (ALIGN_B0 + ALIGN_NB)     // 1782
#define SPK_B0     (GATE_B0 + GATE_NB)       // 1798
#define AUG_B0     (SPK_B0 + SPK_NB)         // 1814
#define GRID       (AUG_B0 + AUG_NB)         // 1830

// Partial buffer layout in ws (floats). Zero atomics for the partials; every
// slot is unconditionally written each launch (no memset needed).
#define P_MEL    0                           // 1000
#define P_ALIGN  (P_MEL + MEL_NB)            // 1000..1782
#define P_GATE   (P_ALIGN + ALIGN_NB)        // 1782..1798
#define P_SPK    (P_GATE + GATE_NB)          // 1798..1862 (64 rows)
#define P_AUG    (P_SPK + 64)                // 1862..1926 (64 rows)

// Clang ext-vector float4 (accepted by __builtin_nontemporal_load).
typedef float vfloat4 __attribute__((ext_vector_type(4)));

// Module-scope completion counter. Zero-initialized at module load; the last
// block resets it to 0 after finalizing, so every subsequent launch (graph
// replay, rocprof replay) starts from 0 again.
__device__ unsigned int g_count = 0u;

__device__ __forceinline__ float waveReduceSum(float v) {
#pragma unroll
    for (int o = 32; o > 0; o >>= 1) v += __shfl_down(v, o, 64);
    return v;
}

// Butterfly all-reduce: every lane ends with the result.
__device__ __forceinline__ float waveAllReduceSum(float v) {
#pragma unroll
    for (int o = 1; o < 64; o <<= 1) v += __shfl_xor(v, o, 64);
    return v;
}
__device__ __forceinline__ float waveAllReduceMax(float v) {
#pragma unroll
    for (int o = 1; o < 64; o <<= 1) v = fmaxf(v, __shfl_xor(v, o, 64));
    return v;
}
// First-occurrence argmax (matches jnp.argmax tie-breaking).
__device__ __forceinline__ void waveAllReduceArgMax(float& v, int& i) {
#pragma unroll
    for (int o = 1; o < 64; o <<= 1) {
        float ov = __shfl_xor(v, o, 64);
        int   oi = __shfl_xor(i, o, 64);
        if (ov > v || (ov == v && oi < i)) { v = ov; i = oi; }
    }
}

// Agent-scope publish of a partial: write-through to the device coherence
// point so the finalizing block (possibly on another XCD) sees it.
__device__ __forceinline__ void partialStore(float* slot, float v) {
    __hip_atomic_store(slot, v, __ATOMIC_RELAXED, __HIP_MEMORY_SCOPE_AGENT);
}
__device__ __forceinline__ float partialLoad(const float* slot) {
    return __hip_atomic_load(slot, __ATOMIC_RELAXED, __HIP_MEMORY_SCOPE_AGENT);
}

// Block reduce -> ONE agent-scope store to a distinct slot (no RMW).
__device__ __forceinline__ void blockReduceStore(float v, float* slot) {
    __shared__ float smem[4];
    const int lane = threadIdx.x & 63;
    const int wid = threadIdx.x >> 6;
    v = waveReduceSum(v);
    if (lane == 0) smem[wid] = v;
    __syncthreads();
    if (threadIdx.x == 0) {
        partialStore(slot, smem[0] + smem[1] + smem[2] + smem[3]);
    }
}

// Nontemporal float4 load (single-use streaming data; early L2/L3 evict).
__device__ __forceinline__ vfloat4 ntload(const float* p) {
    return __builtin_nontemporal_load((const vfloat4*)p);
}

// Alignment penalty contribution for float4 unit u (element e = 4u).
__device__ __forceinline__ float alignContrib(int u, vfloat4 v) {
    const int q = u / 50;                    // e / 200
    const int r = u - q * 50;                // (e % 200) / 4
    const float nf = (float)(q % NDEC) * (1.0f / (float)NDEC);
    const float tb = (float)(4 * r) * (1.0f / (float)TENC);
    float s = 0.f;
#pragma unroll
    for (int j = 0; j < 4; j++) {
        float d = nf - (tb + (float)j * (1.0f / (float)TENC));
        float g = 1.0f - __expf(d * d * -2.5f);   // 1/K_ALIGN = 2.5
        s = fmaf(v[j], g, s);
    }
    return s;
}

__global__ __launch_bounds__(BLOCK) void tacotron2_loss_fused(
    const float* __restrict__ mel_out,
    const float* __restrict__ mel_post,
    const float* __restrict__ gate_out,
    const float* __restrict__ align,
    const float* __restrict__ spk_out,
    const float* __restrict__ aug_out,
    const float* __restrict__ mel_tgt,
    const float* __restrict__ gate_tgt,
    const float* __restrict__ spk_tgt,
    const float* __restrict__ aug_tgt,
    float* __restrict__ ws,
    float* __restrict__ out)
{
    const int bid = blockIdx.x;
    const int t = threadIdx.x;

    if (bid < ALIGN_B0) {
        // ---- MEL: 1280 units/block, 15 float4 loads issued up front ----
        const int base = bid * 1280 + t;             // float4-unit index
        vfloat4 a[5], p[5], tt[5];
#pragma unroll
        for (int k = 0; k < 5; k++) a[k]  = ntload(mel_out  + 4 * (base + 256 * k));
#pragma unroll
        for (int k = 0; k < 5; k++) p[k]  = ntload(mel_post + 4 * (base + 256 * k));
#pragma unroll
        for (int k = 0; k < 5; k++) tt[k] = ntload(mel_tgt  + 4 * (base + 256 * k));
        float s0 = 0.f, s1 = 0.f, d;
#pragma unroll
        for (int k = 0; k < 5; k++) {
            d = a[k][0] - tt[k][0]; s0 = fmaf(d, d, s0);
            d = a[k][1] - tt[k][1]; s1 = fmaf(d, d, s1);
            d = a[k][2] - tt[k][2]; s0 = fmaf(d, d, s0);
            d = a[k][3] - tt[k][3]; s1 = fmaf(d, d, s1);
            d = p[k][0] - tt[k][0]; s0 = fmaf(d, d, s0);
            d = p[k][1] - tt[k][1]; s1 = fmaf(d, d, s1);
            d = p[k][2] - tt[k][2]; s0 = fmaf(d, d, s0);
            d = p[k][3] - tt[k][3]; s1 = fmaf(d, d, s1);
        }
        blockReduceStore(s0 + s1, &ws[P_MEL + bid]);
    } else if (bid < GATE_B0) {
        // ---- ALIGN: 4096 units/block (16 loads), 1024-unit tail block ----
        const int b = bid - ALIGN_B0;
        float s = 0.f;
        if (b < ALIGN_FULL) {
            const int base = b * 4096 + t;
            vfloat4 r[16];
#pragma unroll
            for (int k = 0; k < 16; k++) r[k] = ntload(align + 4 * (base + 256 * k));
#pragma unroll
            for (int k = 0; k < 16; k++) s += alignContrib(base + 256 * k, r[k]);
        } else {
            const int base = ALIGN_FULL * 4096 + t;  // last 1024 units exactly
            vfloat4 r[4];
#pragma unroll
            for (int k = 0; k < 4; k++) r[k] = ntload(align + 4 * (base + 256 * k));
#pragma unroll
            for (int k = 0; k < 4; k++) s += alignContrib(base + 256 * k, r[k]);
        }
        blockReduceStore(s, &ws[P_ALIGN + b]);
    } else if (bid < SPK_B0) {
        // ---- GATE: 4 predicated float4 loads ----
        const int b = bid - GATE_B0;
        const int base = b * 1024 + t;
        float s = 0.f;
#pragma unroll
        for (int k = 0; k < 4; k++) {
            const int u = base + 256 * k;
            if (u < U_GATE) {
                vfloat4 x = ntload(gate_out + 4 * u);
                vfloat4 y = ntload(gate_tgt + 4 * u);
#pragma unroll
                for (int j = 0; j < 4; j++) {
                    float xx = x[j];
                    // softplus(x) = max(x,0) + log1p(exp(-|x|))
                    float sp = fmaxf(xx, 0.f) + log1pf(__expf(-fabsf(xx)));
                    s += sp - xx * y[j];
                }
            }
        }
        blockReduceStore(s, &ws[P_GATE + b]);
    } else if (bid < AUG_B0) {
        // ---- SPEAKER CE: one wave per row, coalesced columns ----
        const int lane = t & 63;
        const int row = (bid - SPK_B0) * 4 + (t >> 6);
        const float* xrow = spk_out + row * NSPK;
        const float* trow = spk_tgt + row * NSPK;
        const int c1 = lane + 64;
        const bool v1 = (c1 < NSPK);
        float x0 = xrow[lane];
        float x1 = v1 ? xrow[c1] : -1e30f;
        float t0 = trow[lane];
        float t1 = v1 ? trow[c1] : -1e30f;

        float mx = waveAllReduceMax(fmaxf(x0, x1));
        float se = waveAllReduceSum(__expf(x0 - mx) + (v1 ? __expf(x1 - mx) : 0.f));
        float bv = (t1 > t0) ? t1 : t0;
        int   bi = (t1 > t0) ? c1 : lane;
        waveAllReduceArgMax(bv, bi);
        float sel = ((lane == bi) ? x0 : 0.f) + ((v1 && c1 == bi) ? x1 : 0.f);
        float xlab = waveAllReduceSum(sel);
        if (lane == 0) {
            partialStore(&ws[P_SPK + row], -(xlab - mx - __logf(se)));
        }
    } else {
        // ---- AUGMENT CE: one wave per row (10 cols in lanes 0..9) ----
        const int lane = t & 63;
        const int row = (bid - AUG_B0) * 4 + (t >> 6);
        const bool v0 = (lane < NAUG);
        const float* xrow = aug_out + row * NAUG;
        const float* trow = aug_tgt + row * NAUG;
        float x0 = v0 ? xrow[lane] : -1e30f;
        float t0 = v0 ? trow[lane] : -1e30f;

        float mx = waveAllReduceMax(x0);
        float se = waveAllReduceSum(v0 ? __expf(x0 - mx) : 0.f);
        float bv = t0; int bi = v0 ? lane : 0x7fffffff;
        waveAllReduceArgMax(bv, bi);
        float xlab = waveAllReduceSum((v0 && lane == bi) ? x0 : 0.f);
        if (lane == 0) {
            partialStore(&ws[P_AUG + row], -(xlab - mx - __logf(se)));
        }
    }

    // ---- Last-block-done finalize (replaces the second kernel launch) ----
    // All writers in this block have issued their agent-scope partial store;
    // __syncthreads() drains them (s_waitcnt vmcnt(0) precedes s_barrier), so
    // thread 0's acq-rel increment properly publishes this block's work.
    __shared__ bool s_last;
    __syncthreads();
    if (t == 0) {
        unsigned int c = __hip_atomic_fetch_add(&g_count, 1u, __ATOMIC_ACQ_REL,
                                                __HIP_MEMORY_SCOPE_AGENT);
        s_last = (c == GRID - 1u);
    }
    __syncthreads();
    if (!s_last) return;

    // This block observed all GRID increments -> every partial is visible at
    // agent scope. Reduce the ~1.9k partials and write the 5 outputs.
    {
        float s_mel = 0.f, s_align = 0.f, s_gate = 0.f, s_spk = 0.f, s_aug = 0.f;

        for (int i = t; i < MEL_NB; i += BLOCK)   s_mel   += partialLoad(&ws[P_MEL + i]);
        for (int i = t; i < ALIGN_NB; i += BLOCK) s_align += partialLoad(&ws[P_ALIGN + i]);
        if (t < GATE_NB) s_gate = partialLoad(&ws[P_GATE + t]);
        if (t < 64)      s_spk  = partialLoad(&ws[P_SPK + t]);
        if (t < 64)      s_aug  = partialLoad(&ws[P_AUG + t]);

        __shared__ float fsm[5][4];
        const int lane = t & 63;
        const int wid = t >> 6;
        s_mel   = waveReduceSum(s_mel);
        s_align = waveReduceSum(s_align);
        s_gate  = waveReduceSum(s_gate);
        s_spk   = waveReduceSum(s_spk);
        s_aug   = waveReduceSum(s_aug);
        if (lane == 0) {
            fsm[0][wid] = s_mel;
            fsm[1][wid] = s_align;
            fsm[2][wid] = s_gate;
            fsm[3][wid] = s_spk;
            fsm[4][wid] = s_aug;
        }
        __syncthreads();

        if (t == 0) {
            float mel_sum   = fsm[0][0] + fsm[0][1] + fsm[0][2] + fsm[0][3];
            float align_sum = fsm[1][0] + fsm[1][1] + fsm[1][2] + fsm[1][3];
            float gate_sum  = fsm[2][0] + fsm[2][1] + fsm[2][2] + fsm[2][3];
            float spk_sum   = fsm[3][0] + fsm[3][1] + fsm[3][2] + fsm[3][3];
            float aug_sum   = fsm[4][0] + fsm[4][1] + fsm[4][2] + fsm[4][3];

            float mel_loss  = mel_sum  * (1.0f / (float)N_MEL);
            float gate_loss = gate_sum * (1.0f / (float)N_GATE);
            float spk_loss  = spk_sum  * (1.0f / (float)BATCH);
            float aug_loss  = aug_sum  * (1.0f / (float)BATCH);
            float align_loss = fabsf(align_sum) * 0.0005f;
            float tmp = mel_loss + gate_loss;
            float total = 10.0f * tmp + 0.1f * (spk_loss + aug_loss) + align_loss;

            out[0] = total;
            out[1] = tmp;
            out[2] = spk_loss;
            out[3] = aug_loss;
            out[4] = align_loss;

            // Reset for the next launch (graph replay / rocprof replay).
            __hip_atomic_store(&g_count, 0u, __ATOMIC_RELAXED,
                               __HIP_MEMORY_SCOPE_AGENT);
        }
    }
}

extern "C" void kernel_launch(void* const* d_in, const int* in_sizes, int n_in,
                              void* d_out, int out_size, void* d_ws, size_t ws_size,
                              hipStream_t stream) {
    const float* mel_out  = (const float*)d_in[0];
    const float* mel_post = (const float*)d_in[1];
    const float* gate_out = (const float*)d_in[2];
    const float* align    = (const float*)d_in[3];
    const float* spk_out  = (const float*)d_in[4];
    const float* aug_out  = (const float*)d_in[5];
    const float* mel_tgt  = (const float*)d_in[6];
    const float* gate_tgt = (const float*)d_in[7];
    const float* spk_tgt  = (const float*)d_in[8];
    const float* aug_tgt  = (const float*)d_in[9];
    // d_in[10] = step (unused by the loss values)

    float* ws = (float*)d_ws;
    float* out = (float*)d_out;

    tacotron2_loss_fused<<<dim3(GRID), dim3(BLOCK), 0, stream>>>(
        mel_out, mel_post, gate_out, align, spk_out, aug_out,
        mel_tgt, gate_tgt, spk_tgt, aug_tgt, ws, out);
}

// Round 3
// 150.998 us; speedup vs baseline: 1.5656x; 1.5656x over previous
//
#include <hip/hip_runtime.h>
#include <hip/hip_bf16.h>

// Problem constants (from reference)
#define BATCH   64
#define NMEL    80
#define TFRAME  1000
#define NDEC    1000
#define TENC    200
#define NSPK    100
#define NAUG    10

// Element counts
#define N_MEL   (BATCH * NMEL * TFRAME)     // 5,120,000
#define N_GATE  (BATCH * TFRAME)            // 64,000
#define N_ALIGN (BATCH * NDEC * TENC)       // 12,800,000

// 4-element (16 B fp32) vector units
#define U_MEL   (N_MEL / 4)                 // 1,280,000
#define U_GATE  (N_GATE / 4)                // 16,000
#define U_ALIGN (N_ALIGN / 4)               // 3,200,000

#define BLOCK 256

// R13 = R12 resubmitted unchanged (R12 bench failed on container acquisition,
// not on the kernel). R12 = exact revert to R10 (149.5 us measured, absmax 0.0).
// R11's single-kernel last-block-done fusion regressed 149.5 -> 236.4 us:
// 1830 co-resident blocks all retiring through an agent-scope ACQ_REL RMW on
// one cache line serialize at the coherence point (each fenced by
// buffer_wbl2/buffer_inv, ~60 ns apiece ~= 110 us tail). The kernel-boundary
// visibility of the two-launch structure costs only ~4-6 us. Keep two kernels.
#define MEL_NB     1000                      // 1280 units/block (5 float4/lane x 3 streams)
#define ALIGN_NB   782                       // 781 x 4096 units + 1 x 1024 tail
#define ALIGN_FULL 781
#define GATE_NB    16                        // 1024 units/block, bounds-checked
#define SPK_NB     16                        // 4 waves/block x 16 = 64 rows
#define AUG_NB     16                        // 4 waves/block x 16 = 64 rows
#define MEL_B0     0
#define ALIGN_B0   (MEL_B0 + MEL_NB)         // 1000
#define GATE_B0    (ALIGN_B0 + ALIGN_NB)     // 1782
#define SPK_B0     (GATE_B0 + GATE_NB)       // 1798
#define AUG_B0     (SPK_B0 + SPK_NB)         // 1814
#define GRID       (AUG_B0 + AUG_NB)         // 1830

// Partial buffer layout in ws (floats). Zero atomics anywhere; every slot is
// unconditionally written each launch (no memset needed).
#define P_MEL    0                           // 1000
#define P_ALIGN  (P_MEL + MEL_NB)            // 1000..1782
#define P_GATE   (P_ALIGN + ALIGN_NB)        // 1782..1798
#define P_SPK    (P_GATE + GATE_NB)          // 1798..1862 (64 rows)
#define P_AUG    (P_SPK + 64)                // 1862..1926 (64 rows)

// Clang ext-vector float4 (accepted by __builtin_nontemporal_load).
typedef float vfloat4 __attribute__((ext_vector_type(4)));

__device__ __forceinline__ float waveReduceSum(float v) {
#pragma unroll
    for (int o = 32; o > 0; o >>= 1) v += __shfl_down(v, o, 64);
    return v;
}

// Butterfly all-reduce: every lane ends with the result.
__device__ __forceinline__ float waveAllReduceSum(float v) {
#pragma unroll
    for (int o = 1; o < 64; o <<= 1) v += __shfl_xor(v, o, 64);
    return v;
}
__device__ __forceinline__ float waveAllReduceMax(float v) {
#pragma unroll
    for (int o = 1; o < 64; o <<= 1) v = fmaxf(v, __shfl_xor(v, o, 64));
    return v;
}
// First-occurrence argmax (matches jnp.argmax tie-breaking).
__device__ __forceinline__ void waveAllReduceArgMax(float& v, int& i) {
#pragma unroll
    for (int o = 1; o < 64; o <<= 1) {
        float ov = __shfl_xor(v, o, 64);
        int   oi = __shfl_xor(i, o, 64);
        if (ov > v || (ov == v && oi < i)) { v = ov; i = oi; }
    }
}

// Block reduce -> ONE plain store to a distinct slot (no atomic, no RMW).
__device__ __forceinline__ void blockReduceStore(float v, float* slot) {
    __shared__ float smem[4];
    const int lane = threadIdx.x & 63;
    const int wid = threadIdx.x >> 6;
    v = waveReduceSum(v);
    if (lane == 0) smem[wid] = v;
    __syncthreads();
    if (threadIdx.x == 0) {
        *slot = smem[0] + smem[1] + smem[2] + smem[3];
    }
}

// Nontemporal float4 load (single-use streaming data; early L2/L3 evict).
__device__ __forceinline__ vfloat4 ntload(const float* p) {
    return __builtin_nontemporal_load((const vfloat4*)p);
}

// Alignment penalty contribution for float4 unit u (element e = 4u).
__device__ __forceinline__ float alignContrib(int u, vfloat4 v) {
    const int q = u / 50;                    // e / 200
    const int r = u - q * 50;                // (e % 200) / 4
    const float nf = (float)(q % NDEC) * (1.0f / (float)NDEC);
    const float tb = (float)(4 * r) * (1.0f / (float)TENC);
    float s = 0.f;
#pragma unroll
    for (int j = 0; j < 4; j++) {
        float d = nf - (tb + (float)j * (1.0f / (float)TENC));
        float g = 1.0f - __expf(d * d * -2.5f);   // 1/K_ALIGN = 2.5
        s = fmaf(v[j], g, s);
    }
    return s;
}

__global__ __launch_bounds__(BLOCK) void tacotron2_loss_reduce(
    const float* __restrict__ mel_out,
    const float* __restrict__ mel_post,
    const float* __restrict__ gate_out,
    const float* __restrict__ align,
    const float* __restrict__ spk_out,
    const float* __restrict__ aug_out,
    const float* __restrict__ mel_tgt,
    const float* __restrict__ gate_tgt,
    const float* __restrict__ spk_tgt,
    const float* __restrict__ aug_tgt,
    float* __restrict__ ws)
{
    const int bid = blockIdx.x;
    const int t = threadIdx.x;

    if (bid < ALIGN_B0) {
        // ---- MEL: 1280 units/block, 15 float4 loads issued up front ----
        const int base = bid * 1280 + t;             // float4-unit index
        vfloat4 a[5], p[5], tt[5];
#pragma unroll
        for (int k = 0; k < 5; k++) a[k]  = ntload(mel_out  + 4 * (base + 256 * k));
#pragma unroll
        for (int k = 0; k < 5; k++) p[k]  = ntload(mel_post + 4 * (base + 256 * k));
#pragma unroll
        for (int k = 0; k < 5; k++) tt[k] = ntload(mel_tgt  + 4 * (base + 256 * k));
        float s0 = 0.f, s1 = 0.f, d;
#pragma unroll
        for (int k = 0; k < 5; k++) {
            d = a[k][0] - tt[k][0]; s0 = fmaf(d, d, s0);
            d = a[k][1] - tt[k][1]; s1 = fmaf(d, d, s1);
            d = a[k][2] - tt[k][2]; s0 = fmaf(d, d, s0);
            d = a[k][3] - tt[k][3]; s1 = fmaf(d, d, s1);
            d = p[k][0] - tt[k][0]; s0 = fmaf(d, d, s0);
            d = p[k][1] - tt[k][1]; s1 = fmaf(d, d, s1);
            d = p[k][2] - tt[k][2]; s0 = fmaf(d, d, s0);
            d = p[k][3] - tt[k][3]; s1 = fmaf(d, d, s1);
        }
        blockReduceStore(s0 + s1, &ws[P_MEL + bid]);
    } else if (bid < GATE_B0) {
        // ---- ALIGN: 4096 units/block (16 loads), 1024-unit tail block ----
        const int b = bid - ALIGN_B0;
        float s = 0.f;
        if (b < ALIGN_FULL) {
            const int base = b * 4096 + t;
            vfloat4 r[16];
#pragma unroll
            for (int k = 0; k < 16; k++) r[k] = ntload(align + 4 * (base + 256 * k));
#pragma unroll
            for (int k = 0; k < 16; k++) s += alignContrib(base + 256 * k, r[k]);
        } else {
            const int base = ALIGN_FULL * 4096 + t;  // last 1024 units exactly
            vfloat4 r[4];
#pragma unroll
            for (int k = 0; k < 4; k++) r[k] = ntload(align + 4 * (base + 256 * k));
#pragma unroll
            for (int k = 0; k < 4; k++) s += alignContrib(base + 256 * k, r[k]);
        }
        blockReduceStore(s, &ws[P_ALIGN + b]);
    } else if (bid < SPK_B0) {
        // ---- GATE: 4 predicated float4 loads ----
        const int b = bid - GATE_B0;
        const int base = b * 1024 + t;
        float s = 0.f;
#pragma unroll
        for (int k = 0; k < 4; k++) {
            const int u = base + 256 * k;
            if (u < U_GATE) {
                vfloat4 x = ntload(gate_out + 4 * u);
                vfloat4 y = ntload(gate_tgt + 4 * u);
#pragma unroll
                for (int j = 0; j < 4; j++) {
                    float xx = x[j];
                    // softplus(x) = max(x,0) + log1p(exp(-|x|))
                    float sp = fmaxf(xx, 0.f) + log1pf(__expf(-fabsf(xx)));
                    s += sp - xx * y[j];
                }
            }
        }
        blockReduceStore(s, &ws[P_GATE + b]);
    } else if (bid < AUG_B0) {
        // ---- SPEAKER CE: one wave per row, coalesced columns ----
        const int lane = t & 63;
        const int row = (bid - SPK_B0) * 4 + (t >> 6);
        const float* xrow = spk_out + row * NSPK;
        const float* trow = spk_tgt + row * NSPK;
        const int c1 = lane + 64;
        const bool v1 = (c1 < NSPK);
        float x0 = xrow[lane];
        float x1 = v1 ? xrow[c1] : -1e30f;
        float t0 = trow[lane];
        float t1 = v1 ? trow[c1] : -1e30f;

        float mx = waveAllReduceMax(fmaxf(x0, x1));
        float se = waveAllReduceSum(__expf(x0 - mx) + (v1 ? __expf(x1 - mx) : 0.f));
        float bv = (t1 > t0) ? t1 : t0;
        int   bi = (t1 > t0) ? c1 : lane;
        waveAllReduceArgMax(bv, bi);
        float sel = ((lane == bi) ? x0 : 0.f) + ((v1 && c1 == bi) ? x1 : 0.f);
        float xlab = waveAllReduceSum(sel);
        if (lane == 0) {
            ws[P_SPK + row] = -(xlab - mx - __logf(se));   // distinct slot per row
        }
    } else {
        // ---- AUGMENT CE: one wave per row (10 cols in lanes 0..9) ----
        const int lane = t & 63;
        const int row = (bid - AUG_B0) * 4 + (t >> 6);
        const bool v0 = (lane < NAUG);
        const float* xrow = aug_out + row * NAUG;
        const float* trow = aug_tgt + row * NAUG;
        float x0 = v0 ? xrow[lane] : -1e30f;
        float t0 = v0 ? trow[lane] : -1e30f;

        float mx = waveAllReduceMax(x0);
        float se = waveAllReduceSum(v0 ? __expf(x0 - mx) : 0.f);
        float bv = t0; int bi = v0 ? lane : 0x7fffffff;
        waveAllReduceArgMax(bv, bi);
        float xlab = waveAllReduceSum((v0 && lane == bi) ? x0 : 0.f);
        if (lane == 0) {
            ws[P_AUG + row] = -(xlab - mx - __logf(se));   // distinct slot per row
        }
    }
}

// Kernel 2: finalize. One block reduces the ~1.9k partials (8 KB, L2/L3-hot)
// and writes the 5 outputs. Kernel boundary provides visibility of k1 stores.
__global__ __launch_bounds__(BLOCK) void tacotron2_loss_finalize(
    const float* __restrict__ ws, float* __restrict__ out)
{
    const int t = threadIdx.x;
    float s_mel = 0.f, s_align = 0.f, s_gate = 0.f, s_spk = 0.f, s_aug = 0.f;

    for (int i = t; i < MEL_NB; i += BLOCK)   s_mel   += ws[P_MEL + i];
    for (int i = t; i < ALIGN_NB; i += BLOCK) s_align += ws[P_ALIGN + i];
    if (t < GATE_NB) s_gate = ws[P_GATE + t];
    if (t < 64)      s_spk  = ws[P_SPK + t];
    if (t < 64)      s_aug  = ws[P_AUG + t];

    __shared__ float smem[5][4];
    const int lane = t & 63;
    const int wid = t >> 6;
    s_mel   = waveReduceSum(s_mel);
    s_align = waveReduceSum(s_align);
    s_gate  = waveReduceSum(s_gate);
    s_spk   = waveReduceSum(s_spk);
    s_aug   = waveReduceSum(s_aug);
    if (lane == 0) {
        smem[0][wid] = s_mel;
        smem[1][wid] = s_align;
        smem[2][wid] = s_gate;
        smem[3][wid] = s_spk;
        smem[4][wid] = s_aug;
    }
    __syncthreads();

    if (t == 0) {
        float mel_sum   = smem[0][0] + smem[0][1] + smem[0][2] + smem[0][3];
        float align_sum = smem[1][0] + smem[1][1] + smem[1][2] + smem[1][3];
        float gate_sum  = smem[2][0] + smem[2][1] + smem[2][2] + smem[2][3];
        float spk_sum   = smem[3][0] + smem[3][1] + smem[3][2] + smem[3][3];
        float aug_sum   = smem[4][0] + smem[4][1] + smem[4][2] + smem[4][3];

        float mel_loss  = mel_sum  * (1.0f / (float)N_MEL);
        float gate_loss = gate_sum * (1.0f / (float)N_GATE);
        float spk_loss  = spk_sum  * (1.0f / (float)BATCH);
        float aug_loss  = aug_sum  * (1.0f / (float)BATCH);
        float align_loss = fabsf(align_sum) * 0.0005f;
        float tmp = mel_loss + gate_loss;
        float total = 10.0f * tmp + 0.1f * (spk_loss + aug_loss) + align_loss;

        out[0] = total;
        out[1] = tmp;
        out[2] = spk_loss;
        out[3] = aug_loss;
        out[4] = align_loss;
    }
}

extern "C" void kernel_launch(void* const* d_in, const int* in_sizes, int n_in,
                              void* d_out, int out_size, void* d_ws, size_t ws_size,
                              hipStream_t stream) {
    const float* mel_out  = (const float*)d_in[0];
    const float* mel_post = (const float*)d_in[1];
    const float* gate_out = (const float*)d_in[2];
    const float* align    = (const float*)d_in[3];
    const float* spk_out  = (const float*)d_in[4];
    const float* aug_out  = (const float*)d_in[5];
    const float* mel_tgt  = (const float*)d_in[6];
    const float* gate_tgt = (const float*)d_in[7];
    const float* spk_tgt  = (const float*)d_in[8];
    const float* aug_tgt  = (const float*)d_in[9];
    // d_in[10] = step (unused by the loss values)

    float* ws = (float*)d_ws;
    float* out = (float*)d_out;

    tacotron2_loss_reduce<<<dim3(GRID), dim3(BLOCK), 0, stream>>>(
        mel_out, mel_post, gate_out, align, spk_out, aug_out,
        mel_tgt, gate_tgt, spk_tgt, aug_tgt, ws);

    tacotron2_loss_finalize<<<dim3(1), dim3(BLOCK), 0, stream>>>(ws, out);
}